// Round 13
// baseline (222.051 us; speedup 1.0000x reference)
//
#include <hip/hip_runtime.h>

// Problem constants
constexpr int B_ = 8, H_ = 64, W_ = 64, C0 = 16, D_ = 128, K_ = 8192;
constexpr int N_ = B_ * H_ * W_;  // 32768 pixels

typedef __attribute__((ext_vector_type(8))) short short8;  // 8 bf16
typedef __attribute__((ext_vector_type(4))) float f32x4;   // MFMA C/D

__device__ __forceinline__ float gelu_f(float x) {
    return 0.5f * x * (1.0f + erff(x * 0.70710678118654752440f));
}

__device__ __forceinline__ unsigned short f2bf(float f) {  // RNE f32->bf16
    unsigned u = __float_as_uint(f);
    u += 0x7fffu + ((u >> 16) & 1u);
    return (unsigned short)(u >> 16);
}

// async global->LDS DMA, 16 B per lane (dest = uniform base + lane*16)
__device__ __forceinline__ void gload_lds16(const void* g, void* l) {
    __builtin_amdgcn_global_load_lds(
        (const __attribute__((address_space(1))) unsigned int*)g,
        (__attribute__((address_space(3))) unsigned int*)l, 16, 0, 0);
}

#define GLOAD_F(dst, addr)                                     \
    asm volatile("global_load_dword %0, %1, off"               \
                 : "=v"(dst)                                   \
                 : "v"(addr))

// ---------------------------------------------------------------------------
// One fused prep kernel (block-range switched):
//  A [0,512):       x NCHW f32 -> xtbf NHWC bf16 (coalesced LDS transpose)
//  B [512,1088):    ew2 -> wtbf2 in MFMA FRAGMENT ORDER [g36][ns8][q4][r16][8e]
//  C [1088,1664):   dw1 -> wtbf3, same fragment order
//  D [1664,1696):   e2n[k] = -0.5*||embed_k||^2 (fp32)
//  E [1696,2720):   embed f32 -> embbf bf16 (decoder gather)
//  F [2720,2800):   ew1 OIHW -> wtb1b [co][kk=t*16+ci, pad 160] bf16
//  G [2800,2928):   partial[n] = 0 (VQ cross-block atomic-merge slots)
//  H [2928,3440):   embq: codebook in fragment order [tile][kk][ns][q][r][8e]
__global__ __launch_bounds__(256) void prep_kernel(
    const float* __restrict__ x, const float* __restrict__ ew1,
    const float* __restrict__ ew2, const float* __restrict__ dw1,
    const float* __restrict__ embed, unsigned short* __restrict__ xtbf,
    unsigned short* __restrict__ wtbf2, unsigned short* __restrict__ wtbf3,
    float* __restrict__ e2n, unsigned short* __restrict__ embbf,
    unsigned short* __restrict__ wtb1b,
    unsigned long long* __restrict__ partial,
    unsigned short* __restrict__ embq) {
    __shared__ float xt[16][66];  // transpose pad (only section A uses it)
    int blk = blockIdx.x;
    int tid = threadIdx.x;
    if (blk < 512) {  // A: coalesced NCHW->NHWC transpose, block = (b,h)
        int b = blk >> 6, h = blk & 63;
        int c = tid >> 4, w4 = tid & 15;
        float4 v = ((const float4*)x)[(b * 16 + c) * 1024 + h * 16 + w4];
        xt[c][w4 * 4 + 0] = v.x;
        xt[c][w4 * 4 + 1] = v.y;
        xt[c][w4 * 4 + 2] = v.z;
        xt[c][w4 * 4 + 3] = v.w;
        __syncthreads();
        int w = tid >> 2, cg = (tid & 3) * 4;
        ushort4 o;
        o.x = f2bf(xt[cg + 0][w]);
        o.y = f2bf(xt[cg + 1][w]);
        o.z = f2bf(xt[cg + 2][w]);
        o.w = f2bf(xt[cg + 3][w]);
        *(ushort4*)(xtbf + (((b * 64 + h) * 64 + w) << 4) + cg) = o;
    } else if (blk < 1664) {  // B/C: 3x3 weights -> fragment order
        const float* src = (blk < 1088) ? ew2 : dw1;
        unsigned short* dst = (blk < 1088) ? wtbf2 : wtbf3;
        int i = (blk - ((blk < 1088) ? 512 : 1088)) * 256 + tid;  // < 147456
        int g = i >> 12, rem = i & 4095;  // g = t*4 + k
        int ns = rem >> 9, q = (rem >> 7) & 3, r = (rem >> 3) & 15, e = rem & 7;
        int t = g >> 2, k = g & 3;
        int co = ns * 16 + r, ci = k * 32 + q * 8 + e;
        dst[i] = f2bf(src[(co * 128 + ci) * 9 + t]);
    } else if (blk < 1696) {  // D: e2n = -||e||^2 / 2
        int k = (blk - 1664) * 256 + tid;
        const float4* e4 = (const float4*)(embed + (size_t)k * 128);
        float s = 0.0f;
#pragma unroll 8
        for (int i = 0; i < 32; ++i) {
            float4 v = e4[i];
            s += v.x * v.x + v.y * v.y + v.z * v.z + v.w * v.w;
        }
        e2n[k] = -0.5f * s;
    } else if (blk < 2720) {  // E: embbf
        int i = (blk - 1696) * 256 + tid;
        float4 v = ((const float4*)embed)[i];
        uint2 o;
        o.x = (unsigned)f2bf(v.x) | ((unsigned)f2bf(v.y) << 16);
        o.y = (unsigned)f2bf(v.z) | ((unsigned)f2bf(v.w) << 16);
        ((uint2*)embbf)[i] = o;
    } else if (blk < 2800) {  // F: wtb1b [128 co][160 kk]
        int i = (blk - 2720) * 256 + tid;  // < 20480
        int co = i / 160, kk = i % 160;
        float v = 0.0f;
        if (kk < 144) {
            int t = kk >> 4, ci = kk & 15;
            v = ew1[(co * 16 + ci) * 9 + t];
        }
        wtb1b[i] = f2bf(v);
    } else if (blk < 2928) {  // G: zero the VQ merge slots
        int i = (blk - 2800) * 256 + tid;  // < 32768
        partial[i] = 0ULL;
    } else {  // H: embq fragment reorder (one 16-B slot per thread)
        int s = (blk - 2928) * 256 + tid;  // < 131072 slots
        int T = s >> 10;
        int rem = s & 1023;  // slot = ((kk*4 + ns)*4 + q)*16 + r
        int kk = rem >> 8, nsp = (rem >> 6) & 3, q = (rem >> 4) & 3,
            r = rem & 15;
        int code = T * 64 + nsp * 16 + r;
        int d0 = kk * 32 + q * 8;
        const float* ep = embed + (size_t)code * 128 + d0;
        unsigned short* op = embq + (size_t)s * 8;
#pragma unroll
        for (int e = 0; e < 8; ++e) op[e] = f2bf(ep[e]);
    }
}

// ---------------------------------------------------------------------------
// conv1: 16->128 3x3 + GELU via MFMA, K=160 (9 taps x 16 ci, zero-padded).
// All 10 weight frags preloaded to regs before the staging barrier (latency
// fully hidden); MFMA loop touches LDS only.
__global__ __launch_bounds__(256, 2) void conv1_mfma_kernel(
    const unsigned short* __restrict__ xtbf,   // NHWC [B,64,64,16] bf16
    const unsigned short* __restrict__ wtb1b,  // [128][160] bf16
    const float* __restrict__ bias,            // [128]
    unsigned short* __restrict__ out) {        // NHWC [B,64,64,128] bf16
    constexpr int LDA = 168;
    __shared__ __align__(16) unsigned short As[64 * LDA];  // 21504 B
    int tid = threadIdx.x;
    int wv = tid >> 6, lane = tid & 63;
    int r = lane & 15, q = lane >> 4;
    int h0 = blockIdx.x & 63, b = blockIdx.x >> 6;

    // preload all weight frags (40 VGPRs) — covered by staging + barrier
    short8 bf1[5][2];
#pragma unroll
    for (int k = 0; k < 5; ++k)
#pragma unroll
        for (int ns = 0; ns < 2; ++ns)
            bf1[k][ns] = *(const short8*)(wtb1b + (wv * 32 + ns * 16 + r) * 160 +
                                          k * 32 + q * 8);

#pragma unroll
    for (int j = 0; j < 5; ++j) {
        int s = tid + j * 256;
        if (s < 1152) {
            int px = s / 18, rem = s % 18;
            int t = rem >> 1, half = rem & 1;
            int hh = h0 + t / 3 - 1, ww = px + t % 3 - 1;
            float4 v = make_float4(0.f, 0.f, 0.f, 0.f);
            if ((unsigned)hh < 64u && (unsigned)ww < 64u)
                v = *(const float4*)(xtbf + (((b * 64 + hh) * 64 + ww) << 4) +
                                     half * 8);
            *(float4*)(As + px * LDA + t * 16 + half * 8) = v;
        } else {
            int z = s - 1152;  // < 128
            int px = z >> 1, half = z & 1;
            *(float4*)(As + px * LDA + 144 + half * 8) =
                make_float4(0.f, 0.f, 0.f, 0.f);
        }
    }
    __syncthreads();

    f32x4 acc[4][2];
#pragma unroll
    for (int ms = 0; ms < 4; ++ms)
#pragma unroll
        for (int ns = 0; ns < 2; ++ns) acc[ms][ns] = (f32x4){0.f, 0.f, 0.f, 0.f};

#pragma unroll
    for (int k = 0; k < 5; ++k) {
        short8 af[4];
#pragma unroll
        for (int ms = 0; ms < 4; ++ms)
            af[ms] = *(const short8*)(As + (ms * 16 + r) * LDA + k * 32 + q * 8);
#pragma unroll
        for (int ms = 0; ms < 4; ++ms)
#pragma unroll
            for (int ns = 0; ns < 2; ++ns)
                acc[ms][ns] = __builtin_amdgcn_mfma_f32_16x16x32_bf16(
                    af[ms], bf1[k][ns], acc[ms][ns], 0, 0, 0);
    }

#pragma unroll
    for (int ns = 0; ns < 2; ++ns) {
        int co = wv * 32 + ns * 16 + r;
        float bv = bias[co];
#pragma unroll
        for (int ms = 0; ms < 4; ++ms)
#pragma unroll
            for (int rg = 0; rg < 4; ++rg) {
                int px = ms * 16 + q * 4 + rg;
                int pix = (b * 64 + h0) * 64 + px;
                out[(size_t)pix * 128 + co] = f2bf(gelu_f(acc[ms][ns][rg] + bv));
            }
    }
}

// ---------------------------------------------------------------------------
// 3x3 128->128 conv + GELU via MFMA, LDS-STAGED WEIGHTS (v11, proven r12).
// Weights pre-reordered to fragment order [g][ns][q][r][8e] (8 KB/group),
// staged per group via 8 linear 1-KB global_load_lds DMAs, double-buffered
// Ws[2], conflict-free lane-linear ds_reads, one barrier per group.
// GATHER: act pixels fetched through the packed VQ result. FUSE: dec2
// (1x1 conv 128->16 + sigmoid) fused into the epilogue (float4 ci-loop).
template <bool OUT_BF16, bool GATHER, bool FUSE>
__global__ __launch_bounds__(256, 2) void conv3x3_mfma_kernel(
    const unsigned short* __restrict__ in,   // NHWC acts, or embbf if GATHER
    const unsigned long long* __restrict__ gidx,  // packed VQ result or null
    const unsigned short* __restrict__ wtb,  // [36][4096] fragment-ordered
    const float* __restrict__ bias,          // [128]
    const float* __restrict__ w2,            // [16][128] fp32 (FUSE)
    const float* __restrict__ b2,            // [16] fp32 (FUSE)
    void* __restrict__ out_) {               // NHWC bf16/fp32, or NCHW if FUSE
    constexpr int LDC = 136;
    __shared__ __align__(16) unsigned short As[3 * 66 * LDC];  // 53856 B
    __shared__ __align__(16) unsigned short Ws[2][4096];       // 16384 B
    __shared__ __align__(16) float ws2[FUSE ? 2048 : 4];
    int tid = threadIdx.x;
    int wv = tid >> 6, lane = tid & 63;
    int r = lane & 15, q = lane >> 4;
    int h0 = blockIdx.x & 63, b = blockIdx.x >> 6;

    // stage weight group 0 (issued first; latency hidden by act staging)
    gload_lds16(wtb + (wv * 2) * 512 + lane * 8, &Ws[0][(wv * 2) * 512]);
    gload_lds16(wtb + (wv * 2 + 1) * 512 + lane * 8,
                &Ws[0][(wv * 2 + 1) * 512]);

    constexpr int NJ = FUSE ? 15 : 13;
    for (int j = 0; j < NJ; ++j) {
        int s = tid + j * 256;
        if (s < 3168) {
            int col = s >> 4, chunk = s & 15;
            int ry = col / 66, cx = col % 66;
            int hh = h0 - 1 + ry, ww = cx - 1;
            float4 v = make_float4(0.f, 0.f, 0.f, 0.f);
            if ((unsigned)hh < 64u && (unsigned)ww < 64u) {
                int pix = (b * 64 + hh) * 64 + ww;
                const unsigned short* src;
                if (GATHER) {
                    int k = 8191 - (int)(unsigned)(gidx[pix] & 0xFFFFFFFFu);
                    src = in + (size_t)k * 128;
                } else {
                    src = in + (size_t)pix * 128;
                }
                v = *(const float4*)(src + chunk * 8);
            }
            *(float4*)(As + col * LDC + chunk * 8) = v;
        } else if (FUSE && s < 3680) {
            int i = s - 3168;  // < 512 float4 slots
            ((float4*)ws2)[i] = ((const float4*)w2)[i];
        }
    }
    __syncthreads();  // act + weight group 0 ready (drains vmcnt)

    f32x4 acc[4][2];
#pragma unroll
    for (int ms = 0; ms < 4; ++ms)
#pragma unroll
        for (int ns = 0; ns < 2; ++ns) acc[ms][ns] = (f32x4){0.f, 0.f, 0.f, 0.f};

    int cur = 0;
#pragma unroll 4
    for (int g = 0; g < 36; ++g) {
        if (g < 35) {  // stage group g+1 into the other buffer
            const unsigned short* wsrc = wtb + (size_t)(g + 1) * 4096;
            unsigned short* dst = &Ws[cur ^ 1][0];
            gload_lds16(wsrc + (wv * 2) * 512 + lane * 8, dst + (wv * 2) * 512);
            gload_lds16(wsrc + (wv * 2 + 1) * 512 + lane * 8,
                        dst + (wv * 2 + 1) * 512);
        }
        int t = g >> 2, k = g & 3;
        int dy = t / 3, dx = t - dy * 3;
        // B-frags from LDS, lane-linear (conflict-free): wave wv owns
        // ns-slices {2wv, 2wv+1} of the [ns8][q4][r16][8e] group tile
        short8 bf0 = *(const short8*)(&Ws[cur][(wv * 2) * 512] + lane * 8);
        short8 bf1 = *(const short8*)(&Ws[cur][(wv * 2 + 1) * 512] + lane * 8);
        short8 af[4];
#pragma unroll
        for (int ms = 0; ms < 4; ++ms) {
            int col = dy * 66 + ms * 16 + r + dx;
            af[ms] = *(const short8*)(As + col * LDC + k * 32 + q * 8);
        }
#pragma unroll
        for (int ms = 0; ms < 4; ++ms) {
            acc[ms][0] = __builtin_amdgcn_mfma_f32_16x16x32_bf16(
                af[ms], bf0, acc[ms][0], 0, 0, 0);
            acc[ms][1] = __builtin_amdgcn_mfma_f32_16x16x32_bf16(
                af[ms], bf1, acc[ms][1], 0, 0, 0);
        }
        __syncthreads();  // staging done + all reads of Ws[cur] done
        cur ^= 1;
    }

    if (!FUSE) {
#pragma unroll
        for (int ns = 0; ns < 2; ++ns) {
            int co = wv * 32 + ns * 16 + r;
            float bv = bias[co];
#pragma unroll
            for (int ms = 0; ms < 4; ++ms)
#pragma unroll
                for (int rg = 0; rg < 4; ++rg) {
                    int px = ms * 16 + q * 4 + rg;
                    int pix = (b * 64 + h0) * 64 + px;
                    float g = gelu_f(acc[ms][ns][rg] + bv);
                    if (OUT_BF16)
                        ((unsigned short*)out_)[(size_t)pix * 128 + co] = f2bf(g);
                    else
                        ((float*)out_)[(size_t)pix * 128 + co] = g;
                }
        }
    } else {
        // bias+GELU -> LDS (reuse As as float[64][132]), then 1x1+sigmoid
        __syncthreads();  // all af reads done before overwrite
        float* gbuf = (float*)As;
#pragma unroll
        for (int ns = 0; ns < 2; ++ns) {
            int co = wv * 32 + ns * 16 + r;
            float bv = bias[co];
#pragma unroll
            for (int ms = 0; ms < 4; ++ms)
#pragma unroll
                for (int rg = 0; rg < 4; ++rg) {
                    int px = ms * 16 + q * 4 + rg;
                    gbuf[px * 132 + co] = gelu_f(acc[ms][ns][rg] + bv);
                }
        }
        __syncthreads();
        int w_ = tid & 63, c0 = (tid >> 6) * 4;
        float a4[4] = {b2[c0], b2[c0 + 1], b2[c0 + 2], b2[c0 + 3]};
#pragma unroll 4
        for (int ci = 0; ci < 128; ci += 4) {
            float4 yv = *(const float4*)&gbuf[w_ * 132 + ci];
#pragma unroll
            for (int jc = 0; jc < 4; ++jc) {
                float4 wv4 = *(const float4*)&ws2[(c0 + jc) * 128 + ci];
                a4[jc] += yv.x * wv4.x + yv.y * wv4.y + yv.z * wv4.z +
                          yv.w * wv4.w;
            }
        }
        float* outp = (float*)out_;
#pragma unroll
        for (int jc = 0; jc < 4; ++jc) {
            float v = 1.0f / (1.0f + expf(-a4[jc]));
            outp[(((size_t)b * 16 + c0 + jc) * 64 + h0) * 64 + w_] = v;
        }
    }
}

// ---------------------------------------------------------------------------
// VQ argmin via bf16 MFMA. v12 = v8 + T4 COUNTED-VMCNT PIPELINE.
// v8's per-tile __syncthreads forced a vmcnt(0) drain of the JUST-ISSUED
// next-tile DMAs -> ~700cy/tile stall (wall 2040cy vs ~1300cy max-pipe).
// v12: 3-deep LDS buffers; staging issued 2 tiles ahead AFTER the barrier
// (overwrite is barrier-separated from last reads; in-wave read-retire is
// guaranteed by compiler lgkmcnt before MFMA use). Per-wave VMEM queue is
// strict {S(4),E(2)} pairs -> derived wait vmcnt(6) (S_it,E_it done;
// S_it+1,E_it+1 in flight), vmcnt(0) only at it=63. sched_barrier(0) after
// each wait (guide rule #18); raw s_barrier (no compiler drain). e2 loads
// via inline-asm into parity register pairs (same counted queue). Pass-end
// atomics transiently inflate the count -> one-time over-wait, harmless.
// Geometry unchanged: wave = 32px x 32codes, acc[2][2], af[4][2] preloaded;
// embq [tile][kk][ns][q][r] conflict-free; 11-bit key, mask 0xFFFFF800.
__global__ __launch_bounds__(256, 2) void vq_mfma_kernel(
    const unsigned short* __restrict__ flatbf,  // [N][128] bf16
    const unsigned short* __restrict__ embq,    // fragment-ordered codebook
    const float* __restrict__ e2n,              // [K] fp32, -||e||^2/2
    unsigned long long* __restrict__ partial) { // [N] packed, zero-inited
    __shared__ __align__(16) unsigned short Bs[3][8192];  // 48 KB, 3-deep
    int tid = threadIdx.x;
    int wv = tid >> 6, lane = tid & 63;
    int r = lane & 15, q = lane >> 4;
    int p_h = wv & 1;   // pixel half: rows p_h*32 + ms*16 + ...
    int c_s = wv >> 1;  // code half of each 64-code tile
    int half = blockIdx.x & 1;
    int m0 = (blockIdx.x >> 1) * 64;
    int kbase = half * 4096;
    int t0 = half * 64;  // first tile index

    // A: 32 px x 128 dims preloaded to regs (8 loads; oldest in the vmcnt
    // queue -> drained by iter 0's counted wait before first MFMA use)
    short8 af[4][2];
#pragma unroll
    for (int kk = 0; kk < 4; ++kk)
#pragma unroll
        for (int ms = 0; ms < 2; ++ms)
            af[kk][ms] = *(const short8*)(
                flatbf + (size_t)(m0 + p_h * 32 + ms * 16 + r) * 128 +
                kk * 32 + q * 8);

    const float* e2p = e2n + kbase + c_s * 32 + r;
    float e2a0, e2a1, e2b0, e2b1;  // parity pairs (even/odd tiles)

    // prologue queue (order matters): S0(4) E0(2) S1(4) E1(2)
    {
        const unsigned short* s0 = embq + (size_t)t0 * 8192;
#pragma unroll
        for (int j = 0; j < 4; ++j) {
            int o = (j * 4 + wv) * 512;
            gload_lds16(s0 + o + lane * 8, &Bs[0][o]);
        }
        GLOAD_F(e2a0, e2p);
        GLOAD_F(e2a1, e2p + 16);
        const unsigned short* s1 = embq + (size_t)(t0 + 1) * 8192;
#pragma unroll
        for (int j = 0; j < 4; ++j) {
            int o = (j * 4 + wv) * 512;
            gload_lds16(s1 + o + lane * 8, &Bs[1][o]);
        }
        GLOAD_F(e2b0, e2p + 64);
        GLOAD_F(e2b1, e2p + 80);
    }

    float best[2][4];
#pragma unroll
    for (int ms = 0; ms < 2; ++ms)
#pragma unroll
        for (int rg = 0; rg < 4; ++rg) best[ms][rg] = -3.4e38f;

    f32x4 acc[2][2];
    const unsigned short* pR = &Bs[0][0];  // read buffer (tile it)
    unsigned short* pW = &Bs[2][0];        // write buffer (tile it+2)

#pragma unroll 2
    for (int it = 0; it < 64; ++it) {
        // counted wait: S_it,E_it retired; S_it+1,E_it+1 stay in flight
        if (it == 63) {
            asm volatile("s_waitcnt vmcnt(0)" ::: "memory");
        } else {
            asm volatile("s_waitcnt vmcnt(6)" ::: "memory");
        }
        __builtin_amdgcn_sched_barrier(0);
        __builtin_amdgcn_s_barrier();

        // acc init from this tile's e2 (parity regs, loaded 2 tiles ago)
        {
            float i0, i1;
            if ((it & 1) == 0) {
                i0 = e2a0;
                i1 = e2a1;
            } else {
                i0 = e2b0;
                i1 = e2b1;
            }
#pragma unroll
            for (int ms = 0; ms < 2; ++ms) {
                acc[ms][0] = (f32x4){i0, i0, i0, i0};
                acc[ms][1] = (f32x4){i1, i1, i1, i1};
            }
        }

        if (it < 62) {  // stage S_{it+2},E_{it+2}; pW held tile it-1 whose
                        // reads all completed before this barrier
            const unsigned short* src = embq + (size_t)(t0 + it + 2) * 8192;
#pragma unroll
            for (int j = 0; j < 4; ++j) {
                int o = (j * 4 + wv) * 512;
                gload_lds16(src + o + lane * 8, pW + o);
            }
            if ((it & 1) == 0) {
                GLOAD_F(e2a0, e2p + (it + 2) * 64);
                GLOAD_F(e2a1, e2p + (it + 2) * 64 + 16);
            } else {
                GLOAD_F(e2b0, e2p + (it + 2) * 64);
                GLOAD_F(e2b1, e2p + (it + 2) * 64 + 16);
            }
        }

        // MFMAs on tile it from pR ([kk][ns][q][r]: lane-linear, 0 conflicts)
#pragma unroll
        for (int kk = 0; kk < 4; ++kk) {
            short8 bf0 = *(const short8*)(pR + kk * 2048 + (c_s * 2) * 512 +
                                          q * 128 + r * 8);
            short8 bf1 = *(const short8*)(pR + kk * 2048 + (c_s * 2 + 1) * 512 +
                                          q * 128 + r * 8);
#pragma unroll
            for (int ms = 0; ms < 2; ++ms) {
                acc[ms][0] = __builtin_amdgcn_mfma_f32_16x16x32_bf16(
                    af[kk][ms], bf0, acc[ms][0], 0, 0, 0);
                acc[ms][1] = __builtin_amdgcn_mfma_f32_16x16x32_bf16(
                    af[kk][ms], bf1, acc[ms][1], 0, 0, 0);
            }
        }

        // epilogue: pack 11-bit key (it5,c_s,ns,r), running max
        unsigned kb = (unsigned)(2047 - ((it & 31) * 64 + c_s * 32 + r));
#pragma unroll
        for (int ms = 0; ms < 2; ++ms)
#pragma unroll
            for (int rg = 0; rg < 4; ++rg) {
                float u0 = __uint_as_float(
                    (__float_as_uint(acc[ms][0][rg]) & 0xFFFFF800u) | kb);
                float u1 = __uint_as_float(
                    (__float_as_uint(acc[ms][1][rg]) & 0xFFFFF800u) |
                    (kb - 16u));
                best[ms][rg] = fmaxf(best[ms][rg], fmaxf(u0, u1));
            }
        if ((it & 31) == 31) {  // pass end: merge r-lanes, atomic, reset
#pragma unroll
            for (int ms = 0; ms < 2; ++ms)
#pragma unroll
                for (int rg = 0; rg < 4; ++rg) {
                    float v = best[ms][rg];
#pragma unroll
                    for (int m = 1; m < 16; m <<= 1)
                        v = fmaxf(v, __shfl_xor(v, m));
                    if (r == 0) {
                        unsigned bits = __float_as_uint(v);
                        int cand = 2047 - (int)(bits & 2047u);
                        int code = kbase + (it >> 5) * 2048 + cand;
                        unsigned sb = (bits & 0x80000000u) ? ~bits
                                                           : (bits | 0x80000000u);
                        unsigned long long packed =
                            ((unsigned long long)sb << 32) |
                            (unsigned)(8191 - code);
                        atomicMax(
                            partial + m0 + p_h * 32 + ms * 16 + q * 4 + rg,
                            packed);
                    }
                    best[ms][rg] = -3.4e38f;
                }
        }

        // rotate the 3-deep buffers
        pR = (pR == &Bs[2][0]) ? &Bs[0][0] : pR + 8192;
        pW = (pW == &Bs[2][0]) ? &Bs[0][0] : pW + 8192;
    }
}

// ---------------------------------------------------------------------------
extern "C" void kernel_launch(void* const* d_in, const int* in_sizes, int n_in,
                              void* d_out, int out_size, void* d_ws,
                              size_t ws_size, hipStream_t stream) {
    const float* x = (const float*)d_in[0];
    const float* ew1 = (const float*)d_in[1];
    const float* eb1 = (const float*)d_in[2];
    const float* ew2 = (const float*)d_in[3];
    const float* eb2 = (const float*)d_in[4];
    const float* embed = (const float*)d_in[5];
    const float* dw1 = (const float*)d_in[6];
    const float* db1 = (const float*)d_in[7];
    const float* dw2 = (const float*)d_in[8];
    const float* db2 = (const float*)d_in[9];
    float* out = (float*)d_out;

    float* e2n = (float*)d_ws;                             // 8192 f
    unsigned long long* partial =
        (unsigned long long*)(e2n + 8192);                 // 32768 u64
    unsigned short* xtbf = (unsigned short*)(partial + 32768);  // 524288 us
    unsigned short* wtb1b = xtbf + 524288;                 // 20480 us
    unsigned short* wtbf2 = wtb1b + 20480;                 // 147456 us
    unsigned short* wtbf3 = wtbf2 + 147456;                // 147456 us
    unsigned short* embbf = wtbf3 + 147456;                // 1048576 us
    unsigned short* abf = embbf + 1048576;                 // 4194304 us
    unsigned short* flatbf = abf + 4194304;                // 4194304 us
    unsigned short* embq = flatbf + 4194304;               // 1048576 us

    prep_kernel<<<3440, 256, 0, stream>>>(x, ew1, ew2, dw1, embed, xtbf, wtbf2,
                                          wtbf3, e2n, embbf, wtb1b, partial,
                                          embq);
    conv1_mfma_kernel<<<512, 256, 0, stream>>>(xtbf, wtb1b, eb1, abf);
    conv3x3_mfma_kernel<true, false, false><<<512, 256, 0, stream>>>(
        abf, nullptr, wtbf2, eb2, nullptr, nullptr, flatbf);
    vq_mfma_kernel<<<1024, 256, 0, stream>>>(flatbf, embq, e2n, partial);
    conv3x3_mfma_kernel<false, true, true><<<512, 256, 0, stream>>>(
        embbf, partial, wtbf3, db1, dw2, db2, out);
}

// Round 14
// 210.071 us; speedup vs baseline: 1.0570x; 1.0570x over previous
//
#include <hip/hip_runtime.h>

// Problem constants
constexpr int B_ = 8, H_ = 64, W_ = 64, C0 = 16, D_ = 128, K_ = 8192;
constexpr int N_ = B_ * H_ * W_;  // 32768 pixels

typedef __attribute__((ext_vector_type(8))) short short8;  // 8 bf16
typedef __attribute__((ext_vector_type(4))) float f32x4;   // MFMA C/D

__device__ __forceinline__ float gelu_f(float x) {
    return 0.5f * x * (1.0f + erff(x * 0.70710678118654752440f));
}

__device__ __forceinline__ unsigned short f2bf(float f) {  // RNE f32->bf16
    unsigned u = __float_as_uint(f);
    u += 0x7fffu + ((u >> 16) & 1u);
    return (unsigned short)(u >> 16);
}

// async global->LDS DMA, 16 B per lane (dest = uniform base + lane*16)
__device__ __forceinline__ void gload_lds16(const void* g, void* l) {
    __builtin_amdgcn_global_load_lds(
        (const __attribute__((address_space(1))) unsigned int*)g,
        (__attribute__((address_space(3))) unsigned int*)l, 16, 0, 0);
}

// ---------------------------------------------------------------------------
// One fused prep kernel (block-range switched):
//  A [0,512):       x NCHW f32 -> xtbf NHWC bf16 (coalesced LDS transpose)
//  B [512,1088):    ew2 -> wtbf2 in MFMA FRAGMENT ORDER [g36][ns8][q4][r16][8e]
//  C [1088,1664):   dw1 -> wtbf3, same fragment order
//  D [1664,1696):   e2n[k] = -0.5*||embed_k||^2 (fp32)
//  E [1696,2720):   embed f32 -> embbf bf16 (decoder gather)
//  F [2720,2800):   ew1 OIHW -> wtb1b [co][kk=t*16+ci, pad 160] bf16
//  G [2800,2928):   partial[n] = 0 (VQ cross-block atomic-merge slots)
//  H [2928,3440):   embq: codebook in fragment order [tile][kk][ns][q][r][8e]
__global__ __launch_bounds__(256) void prep_kernel(
    const float* __restrict__ x, const float* __restrict__ ew1,
    const float* __restrict__ ew2, const float* __restrict__ dw1,
    const float* __restrict__ embed, unsigned short* __restrict__ xtbf,
    unsigned short* __restrict__ wtbf2, unsigned short* __restrict__ wtbf3,
    float* __restrict__ e2n, unsigned short* __restrict__ embbf,
    unsigned short* __restrict__ wtb1b,
    unsigned long long* __restrict__ partial,
    unsigned short* __restrict__ embq) {
    __shared__ float xt[16][66];  // transpose pad (only section A uses it)
    int blk = blockIdx.x;
    int tid = threadIdx.x;
    if (blk < 512) {  // A: coalesced NCHW->NHWC transpose, block = (b,h)
        int b = blk >> 6, h = blk & 63;
        int c = tid >> 4, w4 = tid & 15;
        float4 v = ((const float4*)x)[(b * 16 + c) * 1024 + h * 16 + w4];
        xt[c][w4 * 4 + 0] = v.x;
        xt[c][w4 * 4 + 1] = v.y;
        xt[c][w4 * 4 + 2] = v.z;
        xt[c][w4 * 4 + 3] = v.w;
        __syncthreads();
        int w = tid >> 2, cg = (tid & 3) * 4;
        ushort4 o;
        o.x = f2bf(xt[cg + 0][w]);
        o.y = f2bf(xt[cg + 1][w]);
        o.z = f2bf(xt[cg + 2][w]);
        o.w = f2bf(xt[cg + 3][w]);
        *(ushort4*)(xtbf + (((b * 64 + h) * 64 + w) << 4) + cg) = o;
    } else if (blk < 1664) {  // B/C: 3x3 weights -> fragment order
        const float* src = (blk < 1088) ? ew2 : dw1;
        unsigned short* dst = (blk < 1088) ? wtbf2 : wtbf3;
        int i = (blk - ((blk < 1088) ? 512 : 1088)) * 256 + tid;  // < 147456
        int g = i >> 12, rem = i & 4095;  // g = t*4 + k
        int ns = rem >> 9, q = (rem >> 7) & 3, r = (rem >> 3) & 15, e = rem & 7;
        int t = g >> 2, k = g & 3;
        int co = ns * 16 + r, ci = k * 32 + q * 8 + e;
        dst[i] = f2bf(src[(co * 128 + ci) * 9 + t]);
    } else if (blk < 1696) {  // D: e2n = -||e||^2 / 2
        int k = (blk - 1664) * 256 + tid;
        const float4* e4 = (const float4*)(embed + (size_t)k * 128);
        float s = 0.0f;
#pragma unroll 8
        for (int i = 0; i < 32; ++i) {
            float4 v = e4[i];
            s += v.x * v.x + v.y * v.y + v.z * v.z + v.w * v.w;
        }
        e2n[k] = -0.5f * s;
    } else if (blk < 2720) {  // E: embbf
        int i = (blk - 1696) * 256 + tid;
        float4 v = ((const float4*)embed)[i];
        uint2 o;
        o.x = (unsigned)f2bf(v.x) | ((unsigned)f2bf(v.y) << 16);
        o.y = (unsigned)f2bf(v.z) | ((unsigned)f2bf(v.w) << 16);
        ((uint2*)embbf)[i] = o;
    } else if (blk < 2800) {  // F: wtb1b [128 co][160 kk]
        int i = (blk - 2720) * 256 + tid;  // < 20480
        int co = i / 160, kk = i % 160;
        float v = 0.0f;
        if (kk < 144) {
            int t = kk >> 4, ci = kk & 15;
            v = ew1[(co * 16 + ci) * 9 + t];
        }
        wtb1b[i] = f2bf(v);
    } else if (blk < 2928) {  // G: zero the VQ merge slots
        int i = (blk - 2800) * 256 + tid;  // < 32768
        partial[i] = 0ULL;
    } else {  // H: embq fragment reorder (one 16-B slot per thread)
        int s = (blk - 2928) * 256 + tid;  // < 131072 slots
        int T = s >> 10;
        int rem = s & 1023;  // slot = ((kk*4 + ns)*4 + q)*16 + r
        int kk = rem >> 8, nsp = (rem >> 6) & 3, q = (rem >> 4) & 3,
            r = rem & 15;
        int code = T * 64 + nsp * 16 + r;
        int d0 = kk * 32 + q * 8;
        const float* ep = embed + (size_t)code * 128 + d0;
        unsigned short* op = embq + (size_t)s * 8;
#pragma unroll
        for (int e = 0; e < 8; ++e) op[e] = f2bf(ep[e]);
    }
}

// ---------------------------------------------------------------------------
// conv1: 16->128 3x3 + GELU via MFMA, K=160 (9 taps x 16 ci, zero-padded).
// All 10 weight frags preloaded to regs before the staging barrier (latency
// fully hidden); MFMA loop touches LDS only.
__global__ __launch_bounds__(256, 2) void conv1_mfma_kernel(
    const unsigned short* __restrict__ xtbf,   // NHWC [B,64,64,16] bf16
    const unsigned short* __restrict__ wtb1b,  // [128][160] bf16
    const float* __restrict__ bias,            // [128]
    unsigned short* __restrict__ out) {        // NHWC [B,64,64,128] bf16
    constexpr int LDA = 168;
    __shared__ __align__(16) unsigned short As[64 * LDA];  // 21504 B
    int tid = threadIdx.x;
    int wv = tid >> 6, lane = tid & 63;
    int r = lane & 15, q = lane >> 4;
    int h0 = blockIdx.x & 63, b = blockIdx.x >> 6;

    // preload all weight frags (40 VGPRs) — covered by staging + barrier
    short8 bf1[5][2];
#pragma unroll
    for (int k = 0; k < 5; ++k)
#pragma unroll
        for (int ns = 0; ns < 2; ++ns)
            bf1[k][ns] = *(const short8*)(wtb1b + (wv * 32 + ns * 16 + r) * 160 +
                                          k * 32 + q * 8);

#pragma unroll
    for (int j = 0; j < 5; ++j) {
        int s = tid + j * 256;
        if (s < 1152) {
            int px = s / 18, rem = s % 18;
            int t = rem >> 1, half = rem & 1;
            int hh = h0 + t / 3 - 1, ww = px + t % 3 - 1;
            float4 v = make_float4(0.f, 0.f, 0.f, 0.f);
            if ((unsigned)hh < 64u && (unsigned)ww < 64u)
                v = *(const float4*)(xtbf + (((b * 64 + hh) * 64 + ww) << 4) +
                                     half * 8);
            *(float4*)(As + px * LDA + t * 16 + half * 8) = v;
        } else {
            int z = s - 1152;  // < 128
            int px = z >> 1, half = z & 1;
            *(float4*)(As + px * LDA + 144 + half * 8) =
                make_float4(0.f, 0.f, 0.f, 0.f);
        }
    }
    __syncthreads();

    f32x4 acc[4][2];
#pragma unroll
    for (int ms = 0; ms < 4; ++ms)
#pragma unroll
        for (int ns = 0; ns < 2; ++ns) acc[ms][ns] = (f32x4){0.f, 0.f, 0.f, 0.f};

#pragma unroll
    for (int k = 0; k < 5; ++k) {
        short8 af[4];
#pragma unroll
        for (int ms = 0; ms < 4; ++ms)
            af[ms] = *(const short8*)(As + (ms * 16 + r) * LDA + k * 32 + q * 8);
#pragma unroll
        for (int ms = 0; ms < 4; ++ms)
#pragma unroll
            for (int ns = 0; ns < 2; ++ns)
                acc[ms][ns] = __builtin_amdgcn_mfma_f32_16x16x32_bf16(
                    af[ms], bf1[k][ns], acc[ms][ns], 0, 0, 0);
    }

#pragma unroll
    for (int ns = 0; ns < 2; ++ns) {
        int co = wv * 32 + ns * 16 + r;
        float bv = bias[co];
#pragma unroll
        for (int ms = 0; ms < 4; ++ms)
#pragma unroll
            for (int rg = 0; rg < 4; ++rg) {
                int px = ms * 16 + q * 4 + rg;
                int pix = (b * 64 + h0) * 64 + px;
                out[(size_t)pix * 128 + co] = f2bf(gelu_f(acc[ms][ns][rg] + bv));
            }
    }
}

// ---------------------------------------------------------------------------
// 3x3 128->128 conv + GELU via MFMA, LDS-STAGED WEIGHTS (proven r12 form).
// Weights pre-reordered to fragment order [g][ns][q][r][8e] (8 KB/group),
// staged per group via 8 linear 1-KB global_load_lds DMAs, double-buffered
// Ws[2], conflict-free lane-linear ds_reads, one barrier per group.
// GATHER: act pixels fetched through the packed VQ result. FUSE: dec2
// (1x1 conv 128->16 + sigmoid) fused into the epilogue (float4 ci-loop).
template <bool OUT_BF16, bool GATHER, bool FUSE>
__global__ __launch_bounds__(256, 2) void conv3x3_mfma_kernel(
    const unsigned short* __restrict__ in,   // NHWC acts, or embbf if GATHER
    const unsigned long long* __restrict__ gidx,  // packed VQ result or null
    const unsigned short* __restrict__ wtb,  // [36][4096] fragment-ordered
    const float* __restrict__ bias,          // [128]
    const float* __restrict__ w2,            // [16][128] fp32 (FUSE)
    const float* __restrict__ b2,            // [16] fp32 (FUSE)
    void* __restrict__ out_) {               // NHWC bf16/fp32, or NCHW if FUSE
    constexpr int LDC = 136;
    __shared__ __align__(16) unsigned short As[3 * 66 * LDC];  // 53856 B
    __shared__ __align__(16) unsigned short Ws[2][4096];       // 16384 B
    __shared__ __align__(16) float ws2[FUSE ? 2048 : 4];
    int tid = threadIdx.x;
    int wv = tid >> 6, lane = tid & 63;
    int r = lane & 15, q = lane >> 4;
    int h0 = blockIdx.x & 63, b = blockIdx.x >> 6;

    // stage weight group 0 (issued first; latency hidden by act staging)
    gload_lds16(wtb + (wv * 2) * 512 + lane * 8, &Ws[0][(wv * 2) * 512]);
    gload_lds16(wtb + (wv * 2 + 1) * 512 + lane * 8,
                &Ws[0][(wv * 2 + 1) * 512]);

    constexpr int NJ = FUSE ? 15 : 13;
    for (int j = 0; j < NJ; ++j) {
        int s = tid + j * 256;
        if (s < 3168) {
            int col = s >> 4, chunk = s & 15;
            int ry = col / 66, cx = col % 66;
            int hh = h0 - 1 + ry, ww = cx - 1;
            float4 v = make_float4(0.f, 0.f, 0.f, 0.f);
            if ((unsigned)hh < 64u && (unsigned)ww < 64u) {
                int pix = (b * 64 + hh) * 64 + ww;
                const unsigned short* src;
                if (GATHER) {
                    int k = 8191 - (int)(unsigned)(gidx[pix] & 0xFFFFFFFFu);
                    src = in + (size_t)k * 128;
                } else {
                    src = in + (size_t)pix * 128;
                }
                v = *(const float4*)(src + chunk * 8);
            }
            *(float4*)(As + col * LDC + chunk * 8) = v;
        } else if (FUSE && s < 3680) {
            int i = s - 3168;  // < 512 float4 slots
            ((float4*)ws2)[i] = ((const float4*)w2)[i];
        }
    }
    __syncthreads();  // act + weight group 0 ready (drains vmcnt)

    f32x4 acc[4][2];
#pragma unroll
    for (int ms = 0; ms < 4; ++ms)
#pragma unroll
        for (int ns = 0; ns < 2; ++ns) acc[ms][ns] = (f32x4){0.f, 0.f, 0.f, 0.f};

    int cur = 0;
#pragma unroll 4
    for (int g = 0; g < 36; ++g) {
        if (g < 35) {  // stage group g+1 into the other buffer
            const unsigned short* wsrc = wtb + (size_t)(g + 1) * 4096;
            unsigned short* dst = &Ws[cur ^ 1][0];
            gload_lds16(wsrc + (wv * 2) * 512 + lane * 8, dst + (wv * 2) * 512);
            gload_lds16(wsrc + (wv * 2 + 1) * 512 + lane * 8,
                        dst + (wv * 2 + 1) * 512);
        }
        int t = g >> 2, k = g & 3;
        int dy = t / 3, dx = t - dy * 3;
        // B-frags from LDS, lane-linear (conflict-free): wave wv owns
        // ns-slices {2wv, 2wv+1} of the [ns8][q4][r16][8e] group tile
        short8 bf0 = *(const short8*)(&Ws[cur][(wv * 2) * 512] + lane * 8);
        short8 bf1 = *(const short8*)(&Ws[cur][(wv * 2 + 1) * 512] + lane * 8);
        short8 af[4];
#pragma unroll
        for (int ms = 0; ms < 4; ++ms) {
            int col = dy * 66 + ms * 16 + r + dx;
            af[ms] = *(const short8*)(As + col * LDC + k * 32 + q * 8);
        }
#pragma unroll
        for (int ms = 0; ms < 4; ++ms) {
            acc[ms][0] = __builtin_amdgcn_mfma_f32_16x16x32_bf16(
                af[ms], bf0, acc[ms][0], 0, 0, 0);
            acc[ms][1] = __builtin_amdgcn_mfma_f32_16x16x32_bf16(
                af[ms], bf1, acc[ms][1], 0, 0, 0);
        }
        __syncthreads();  // staging done + all reads of Ws[cur] done
        cur ^= 1;
    }

    if (!FUSE) {
#pragma unroll
        for (int ns = 0; ns < 2; ++ns) {
            int co = wv * 32 + ns * 16 + r;
            float bv = bias[co];
#pragma unroll
            for (int ms = 0; ms < 4; ++ms)
#pragma unroll
                for (int rg = 0; rg < 4; ++rg) {
                    int px = ms * 16 + q * 4 + rg;
                    int pix = (b * 64 + h0) * 64 + px;
                    float g = gelu_f(acc[ms][ns][rg] + bv);
                    if (OUT_BF16)
                        ((unsigned short*)out_)[(size_t)pix * 128 + co] = f2bf(g);
                    else
                        ((float*)out_)[(size_t)pix * 128 + co] = g;
                }
        }
    } else {
        // bias+GELU -> LDS (reuse As as float[64][132]), then 1x1+sigmoid
        __syncthreads();  // all af reads done before overwrite
        float* gbuf = (float*)As;
#pragma unroll
        for (int ns = 0; ns < 2; ++ns) {
            int co = wv * 32 + ns * 16 + r;
            float bv = bias[co];
#pragma unroll
            for (int ms = 0; ms < 4; ++ms)
#pragma unroll
                for (int rg = 0; rg < 4; ++rg) {
                    int px = ms * 16 + q * 4 + rg;
                    gbuf[px * 132 + co] = gelu_f(acc[ms][ns][rg] + bv);
                }
        }
        __syncthreads();
        int w_ = tid & 63, c0 = (tid >> 6) * 4;
        float a4[4] = {b2[c0], b2[c0 + 1], b2[c0 + 2], b2[c0 + 3]};
#pragma unroll 4
        for (int ci = 0; ci < 128; ci += 4) {
            float4 yv = *(const float4*)&gbuf[w_ * 132 + ci];
#pragma unroll
            for (int jc = 0; jc < 4; ++jc) {
                float4 wv4 = *(const float4*)&ws2[(c0 + jc) * 128 + ci];
                a4[jc] += yv.x * wv4.x + yv.y * wv4.y + yv.z * wv4.z +
                          yv.w * wv4.w;
            }
        }
        float* outp = (float*)out_;
#pragma unroll
        for (int jc = 0; jc < 4; ++jc) {
            float v = 1.0f / (1.0f + expf(-a4[jc]));
            outp[(((size_t)b * 16 + c0 + jc) * 64 + h0) * 64 + w_] = v;
        }
    }
}

// ---------------------------------------------------------------------------
// VQ argmin via bf16 MFMA. LDS-STAGED GEMM v8 (PROVEN ~79us — restored from
// the v12 counted-vmcnt attempt whose 48 KB LDS cut residency 2.75->2
// blocks/CU and regressed to 95us). At ~85% combined issue (MfmaUtil 38 +
// VALU 47), 0 bank conflicts, 12.4 MB FETCH: this structure's knee.
// embq layout [tile][kk][ns][q][r]: conflict-free ds_read.
// 16 linear 1-KB global_load_lds DMAs/tile, double-buffered, 1 barrier/tile.
// Wave = 32px x 32codes: acc[2][2]=16 AGPR, af[4][2]=32 regs, 44 arch VGPR
// -> ~2.75 blocks/CU. Two 32-tile passes; 11-bit key, mask 0xFFFFF800.
// Cross-block: atomicMax on (sortable<<32 | 8191-code).
__global__ __launch_bounds__(256, 2) void vq_mfma_kernel(
    const unsigned short* __restrict__ flatbf,  // [N][128] bf16
    const unsigned short* __restrict__ embq,    // fragment-ordered codebook
    const float* __restrict__ e2n,              // [K] fp32, -||e||^2/2
    unsigned long long* __restrict__ partial) { // [N] packed, zero-inited
    __shared__ __align__(16) unsigned short Bs[2][8192];  // 2 x 16 KB
    int tid = threadIdx.x;
    int wv = tid >> 6, lane = tid & 63;
    int r = lane & 15, q = lane >> 4;
    int p_h = wv & 1;   // pixel half: rows p_h*32 + ms*16 + ...
    int c_s = wv >> 1;  // code half of each 64-code tile
    int half = blockIdx.x & 1;
    int m0 = (blockIdx.x >> 1) * 64;
    int kbase = half * 4096;
    int t0 = half * 64;  // first tile index

    // A: 32 px x 128 dims preloaded to regs (8 gather loads, once)
    short8 af[4][2];
#pragma unroll
    for (int kk = 0; kk < 4; ++kk)
#pragma unroll
        for (int ms = 0; ms < 2; ++ms)
            af[kk][ms] = *(const short8*)(
                flatbf + (size_t)(m0 + p_h * 32 + ms * 16 + r) * 128 +
                kk * 32 + q * 8);

    const float* e2p = e2n + kbase + c_s * 32 + r;
    float e2a = e2p[0], e2b = e2p[16];  // it=0 init values
    float e2nx0 = 0.f, e2nx1 = 0.f;

    // stage tile 0 into Bs[0]
    {
        const unsigned short* src = embq + (size_t)t0 * 8192;
#pragma unroll
        for (int j = 0; j < 4; ++j) {
            int o = (j * 4 + wv) * 512;  // shorts (1 KB per DMA)
            gload_lds16(src + o + lane * 8, &Bs[0][o]);
        }
    }

    float best[2][4];
#pragma unroll
    for (int ms = 0; ms < 2; ++ms)
#pragma unroll
        for (int rg = 0; rg < 4; ++rg) best[ms][rg] = -3.4e38f;

    __syncthreads();  // tile 0 ready (barrier drains vmcnt)

    f32x4 acc[2][2];
#pragma unroll
    for (int ms = 0; ms < 2; ++ms) {
        acc[ms][0] = (f32x4){e2a, e2a, e2a, e2a};
        acc[ms][1] = (f32x4){e2b, e2b, e2b, e2b};
    }

    int cur = 0;
#pragma unroll 1
    for (int it = 0; it < 64; ++it) {
        if (it < 63) {  // stage tile it+1 into the other buffer
            const unsigned short* src = embq + (size_t)(t0 + it + 1) * 8192;
            unsigned short* dst = &Bs[cur ^ 1][0];
#pragma unroll
            for (int j = 0; j < 4; ++j) {
                int o = (j * 4 + wv) * 512;
                gload_lds16(src + o + lane * 8, dst + o);
            }
            // e2 for next tile (consumed at reinit, ~whole tile of lead)
            e2nx0 = e2p[(it + 1) * 64];
            e2nx1 = e2p[(it + 1) * 64 + 16];
        }
        const unsigned short* bb = &Bs[cur][0];
#pragma unroll
        for (int kk = 0; kk < 4; ++kk) {
            // [kk][ns][q][r] layout: lane l reads byte l*16 of its ns-block
            short8 bf0 = *(const short8*)(bb + kk * 2048 + (c_s * 2) * 512 +
                                          q * 128 + r * 8);
            short8 bf1 = *(const short8*)(bb + kk * 2048 + (c_s * 2 + 1) * 512 +
                                          q * 128 + r * 8);
#pragma unroll
            for (int ms = 0; ms < 2; ++ms) {
                acc[ms][0] = __builtin_amdgcn_mfma_f32_16x16x32_bf16(
                    af[kk][ms], bf0, acc[ms][0], 0, 0, 0);
                acc[ms][1] = __builtin_amdgcn_mfma_f32_16x16x32_bf16(
                    af[kk][ms], bf1, acc[ms][1], 0, 0, 0);
            }
        }
        // epilogue: pack 11-bit key (it5,c_s,ns,r), running max
        unsigned kb = (unsigned)(2047 - ((it & 31) * 64 + c_s * 32 + r));
#pragma unroll
        for (int ms = 0; ms < 2; ++ms)
#pragma unroll
            for (int rg = 0; rg < 4; ++rg) {
                float u0 = __uint_as_float(
                    (__float_as_uint(acc[ms][0][rg]) & 0xFFFFF800u) | kb);
                float u1 = __uint_as_float(
                    (__float_as_uint(acc[ms][1][rg]) & 0xFFFFF800u) |
                    (kb - 16u));
                best[ms][rg] = fmaxf(best[ms][rg], fmaxf(u0, u1));
            }
        if ((it & 31) == 31) {  // pass end: merge r-lanes, atomic, reset
#pragma unroll
            for (int ms = 0; ms < 2; ++ms)
#pragma unroll
                for (int rg = 0; rg < 4; ++rg) {
                    float v = best[ms][rg];
#pragma unroll
                    for (int m = 1; m < 16; m <<= 1)
                        v = fmaxf(v, __shfl_xor(v, m));
                    if (r == 0) {
                        unsigned bits = __float_as_uint(v);
                        int cand = 2047 - (int)(bits & 2047u);
                        int code = kbase + (it >> 5) * 2048 + cand;
                        unsigned sb = (bits & 0x80000000u) ? ~bits
                                                           : (bits | 0x80000000u);
                        unsigned long long packed =
                            ((unsigned long long)sb << 32) |
                            (unsigned)(8191 - code);
                        atomicMax(
                            partial + m0 + p_h * 32 + ms * 16 + q * 4 + rg,
                            packed);
                    }
                    best[ms][rg] = -3.4e38f;
                }
        }
        if (it < 63) {  // reinit acc for next tile's codes
#pragma unroll
            for (int ms = 0; ms < 2; ++ms) {
                acc[ms][0] = (f32x4){e2nx0, e2nx0, e2nx0, e2nx0};
                acc[ms][1] = (f32x4){e2nx1, e2nx1, e2nx1, e2nx1};
            }
        }
        __syncthreads();  // staging done + all reads of Bs[cur] done
        cur ^= 1;
    }
}

// ---------------------------------------------------------------------------
extern "C" void kernel_launch(void* const* d_in, const int* in_sizes, int n_in,
                              void* d_out, int out_size, void* d_ws,
                              size_t ws_size, hipStream_t stream) {
    const float* x = (const float*)d_in[0];
    const float* ew1 = (const float*)d_in[1];
    const float* eb1 = (const float*)d_in[2];
    const float* ew2 = (const float*)d_in[3];
    const float* eb2 = (const float*)d_in[4];
    const float* embed = (const float*)d_in[5];
    const float* dw1 = (const float*)d_in[6];
    const float* db1 = (const float*)d_in[7];
    const float* dw2 = (const float*)d_in[8];
    const float* db2 = (const float*)d_in[9];
    float* out = (float*)d_out;

    float* e2n = (float*)d_ws;                             // 8192 f
    unsigned long long* partial =
        (unsigned long long*)(e2n + 8192);                 // 32768 u64
    unsigned short* xtbf = (unsigned short*)(partial + 32768);  // 524288 us
    unsigned short* wtb1b = xtbf + 524288;                 // 20480 us
    unsigned short* wtbf2 = wtb1b + 20480;                 // 147456 us
    unsigned short* wtbf3 = wtbf2 + 147456;                // 147456 us
    unsigned short* embbf = wtbf3 + 147456;                // 1048576 us
    unsigned short* abf = embbf + 1048576;                 // 4194304 us
    unsigned short* flatbf = abf + 4194304;                // 4194304 us
    unsigned short* embq = flatbf + 4194304;               // 1048576 us

    prep_kernel<<<3440, 256, 0, stream>>>(x, ew1, ew2, dw1, embed, xtbf, wtbf2,
                                          wtbf3, e2n, embbf, wtb1b, partial,
                                          embq);
    conv1_mfma_kernel<<<512, 256, 0, stream>>>(xtbf, wtb1b, eb1, abf);
    conv3x3_mfma_kernel<true, false, false><<<512, 256, 0, stream>>>(
        abf, nullptr, wtbf2, eb2, nullptr, nullptr, flatbf);
    vq_mfma_kernel<<<1024, 256, 0, stream>>>(flatbf, embq, e2n, partial);
    conv3x3_mfma_kernel<false, true, true><<<512, 256, 0, stream>>>(
        embbf, partial, wtbf3, db1, dw2, db2, out);
}